// Round 1
// baseline (84.477 us; speedup 1.0000x reference)
//
#include <hip/hip_runtime.h>
#include <math.h>

#define BATCH 8
#define NPTS 256
#define HDIM 128

// ---------------------------------------------------------------------------
// Kernel 1: per-row projections.
//   A[t, c]  = sum_k h[t,k] * W1[k, c]            (Wa = W1[:H])
//   Bb[t, c] = sum_k h[t,k] * W1[H+k, c] + b1[c]  (Wb = W1[H:2H], bias folded)
// One block per row t (2048 blocks, 128 threads = channel c).
// ---------------------------------------------------------------------------
__global__ __launch_bounds__(HDIM) void evh_prep_kernel(
    const float* __restrict__ h, const float* __restrict__ W1,
    const float* __restrict__ b1, float* __restrict__ A, float* __restrict__ Bb)
{
    __shared__ float hrow[HDIM];
    const int t = blockIdx.x;
    const int c = threadIdx.x;
    hrow[c] = h[t * HDIM + c];
    __syncthreads();

    float a = 0.f, bsum = 0.f;
#pragma unroll 8
    for (int k = 0; k < HDIM; ++k) {
        const float hv = hrow[k];
        a    = fmaf(hv, W1[k * HDIM + c], a);
        bsum = fmaf(hv, W1[(HDIM + k) * HDIM + c], bsum);
    }
    A[t * HDIM + c]  = a;
    Bb[t * HDIM + c] = bsum + b1[c];
}

// ---------------------------------------------------------------------------
// Kernel 2: pairwise pass. One block per (b, i): 2048 blocks, 256 threads
// (4 waves). Wave w owns j in [w*64, w*64+64); lane l owns channels 2l,2l+1.
// Per j: pre = A[j] + Bb[i] + dist*wd; coeff = silu(pre)@W2 + b2 via
// wave shuffle reduction; v += coeff * (pos[j]-pos[i]).
// ---------------------------------------------------------------------------
__global__ __launch_bounds__(256) void evh_pair_kernel(
    const float* __restrict__ A, const float* __restrict__ Bb,
    const float* __restrict__ pos, const float* __restrict__ W1,
    const float* __restrict__ W2, const float* __restrict__ b2,
    float* __restrict__ out)
{
    const int blk  = blockIdx.x;      // 0..2047
    const int b    = blk >> 8;        // batch index
    const int i    = blk & 255;       // target point within batch
    const int tid  = threadIdx.x;
    const int wave = tid >> 6;
    const int lane = tid & 63;
    const int c0   = lane * 2;        // two channels per lane

    const int row_i = b * NPTS + i;

    const float2 bi = *reinterpret_cast<const float2*>(&Bb[row_i * HDIM + c0]);
    const float2 wd = *reinterpret_cast<const float2*>(&W1[2 * HDIM * HDIM + c0]);
    const float2 w2 = *reinterpret_cast<const float2*>(&W2[c0]);
    const float  b2v = b2[0];
    const float  pix = pos[row_i * 3 + 0];
    const float  piy = pos[row_i * 3 + 1];
    const float  piz = pos[row_i * 3 + 2];

    float vx = 0.f, vy = 0.f, vz = 0.f;

    const int jbase = b * NPTS + wave * 64;   // this wave's 64 source rows
    for (int jj = 0; jj < 64; ++jj) {
        const int row_j = jbase + jj;
        const float2 a = *reinterpret_cast<const float2*>(&A[row_j * HDIM + c0]);
        const float dx = pos[row_j * 3 + 0] - pix;
        const float dy = pos[row_j * 3 + 1] - piy;
        const float dz = pos[row_j * 3 + 2] - piz;
        const float dist = sqrtf(dx * dx + dy * dy + dz * dz);  // 0 at j==i

        const float pre0 = a.x + bi.x + dist * wd.x;
        const float pre1 = a.y + bi.y + dist * wd.y;
        // silu(x) = x / (1 + exp(-x))
        const float s0 = pre0 / (1.f + __expf(-pre0));
        const float s1 = pre1 / (1.f + __expf(-pre1));
        float s = s0 * w2.x + s1 * w2.y;

        // full 64-lane butterfly reduce: every lane ends with the sum
#pragma unroll
        for (int off = 32; off >= 1; off >>= 1)
            s += __shfl_xor(s, off, 64);

        const float coeff = s + b2v;
        vx = fmaf(coeff, dx, vx);
        vy = fmaf(coeff, dy, vy);
        vz = fmaf(coeff, dz, vz);
    }

    __shared__ float vsh[4][3];
    if (lane == 0) {
        vsh[wave][0] = vx; vsh[wave][1] = vy; vsh[wave][2] = vz;
    }
    __syncthreads();
    if (tid < 3) {
        out[row_i * 3 + tid] =
            vsh[0][tid] + vsh[1][tid] + vsh[2][tid] + vsh[3][tid];
    }
}

extern "C" void kernel_launch(void* const* d_in, const int* in_sizes, int n_in,
                              void* d_out, int out_size, void* d_ws, size_t ws_size,
                              hipStream_t stream) {
    const float* h   = (const float*)d_in[0];  // (2048, 128)
    const float* pos = (const float*)d_in[1];  // (2048, 3)
    // d_in[2] = batch indices (int64) — layout is contiguous per batch, unused
    const float* W1  = (const float*)d_in[3];  // (257, 128)
    const float* b1  = (const float*)d_in[4];  // (128,)
    const float* W2  = (const float*)d_in[5];  // (128, 1)
    const float* b2  = (const float*)d_in[6];  // (1,)
    float* out = (float*)d_out;                // (2048, 3)

    const int TOTAL = BATCH * NPTS;            // 2048
    float* A  = (float*)d_ws;                  // 2048*128 floats = 1 MB
    float* Bb = A + TOTAL * HDIM;              // 2048*128 floats = 1 MB

    evh_prep_kernel<<<TOTAL, HDIM, 0, stream>>>(h, W1, b1, A, Bb);
    evh_pair_kernel<<<TOTAL, 256, 0, stream>>>(A, Bb, pos, W1, W2, b2, out);
}

// Round 2
// 37.894 us; speedup vs baseline: 2.2293x; 2.2293x over previous
//
#include <hip/hip_runtime.h>
#include <math.h>

#define BATCH 8
#define NPTS  256
#define HDIM  128
#define TOTAL (BATCH * NPTS)   // 2048
#define IT    2                // targets (i) per block in the pair kernel

// ---------------------------------------------------------------------------
// Kernel 1: per-row projections.
//   A[t,c]  = sum_k h[t,k] * W1[k,c]          -> stored channel-major, pair-
//             interleaved: A_T2[(c>>1)*2*TOTAL + 2*t + (c&1)]
//   Bb[t,c] = sum_k h[t,k] * W1[H+k,c] + b1[c] (row-major, read as uniforms)
// One block per row t (2048 blocks, 128 threads = channel c).
// ---------------------------------------------------------------------------
__global__ __launch_bounds__(HDIM) void evh_prep_kernel(
    const float* __restrict__ h, const float* __restrict__ W1,
    const float* __restrict__ b1, float* __restrict__ A_T2,
    float* __restrict__ Bb)
{
    __shared__ float hrow[HDIM];
    const int t = blockIdx.x;
    const int c = threadIdx.x;
    hrow[c] = h[t * HDIM + c];
    __syncthreads();

    float a = 0.f, bsum = 0.f;
#pragma unroll 8
    for (int k = 0; k < HDIM; ++k) {
        const float hv = hrow[k];
        a    = fmaf(hv, W1[k * HDIM + c], a);
        bsum = fmaf(hv, W1[(HDIM + k) * HDIM + c], bsum);
    }
    A_T2[(c >> 1) * (2 * TOTAL) + 2 * t + (c & 1)] = a;
    Bb[t * HDIM + c] = bsum + b1[c];
}

// ---------------------------------------------------------------------------
// Kernel 2: pairwise pass, channel-serial layout.
// Block = (batch b, IT consecutive targets i). 256 threads, thread = source j.
// Per channel-pair c2: one coalesced float2 read of A, uniform (scalar) reads
// of Bb/wd/W2; silu + dot-with-W2 accumulate IN REGISTER per thread — no
// cross-lane ops in the hot loop. One block-wide 3-vector reduction at the end.
// ---------------------------------------------------------------------------
__global__ __launch_bounds__(256) void evh_pair_kernel(
    const float* __restrict__ A_T2, const float* __restrict__ Bb,
    const float* __restrict__ pos, const float* __restrict__ W1,
    const float* __restrict__ W2, const float* __restrict__ b2,
    float* __restrict__ out)
{
    const int blk = blockIdx.x;                 // 0 .. 2048/IT-1
    const int b   = blk / (NPTS / IT);
    const int i0  = (blk % (NPTS / IT)) * IT;
    const int tid = threadIdx.x;                // = j within batch
    const int brow  = b * NPTS;
    const int row_j = brow + tid;

    const float pjx = pos[row_j * 3 + 0];
    const float pjy = pos[row_j * 3 + 1];
    const float pjz = pos[row_j * 3 + 2];

    float dx[IT], dy[IT], dz[IT], dist[IT];
#pragma unroll
    for (int s = 0; s < IT; ++s) {
        const int row_i = brow + i0 + s;
        dx[s] = pjx - pos[row_i * 3 + 0];       // diff[b,i,j] = pos_j - pos_i
        dy[s] = pjy - pos[row_i * 3 + 1];
        dz[s] = pjz - pos[row_i * 3 + 2];
        dist[s] = sqrtf(dx[s] * dx[s] + dy[s] * dy[s] + dz[s] * dz[s]);
    }

    const float* __restrict__ wdp = W1 + 2 * HDIM * HDIM;  // W1[2H] row
    float acc[IT];
#pragma unroll
    for (int s = 0; s < IT; ++s) acc[s] = 0.f;

#pragma unroll 8
    for (int c2 = 0; c2 < HDIM / 2; ++c2) {
        const float2 a  = *reinterpret_cast<const float2*>(
                              &A_T2[c2 * (2 * TOTAL) + 2 * row_j]);
        const float2 wd = *reinterpret_cast<const float2*>(&wdp[2 * c2]);
        const float2 w2 = *reinterpret_cast<const float2*>(&W2[2 * c2]);
#pragma unroll
        for (int s = 0; s < IT; ++s) {
            const float2 bb = *reinterpret_cast<const float2*>(
                                  &Bb[(brow + i0 + s) * HDIM + 2 * c2]);
            const float pre0 = fmaf(dist[s], wd.x, a.x + bb.x);
            const float pre1 = fmaf(dist[s], wd.y, a.y + bb.y);
            const float e0 = __expf(-pre0);
            const float e1 = __expf(-pre1);
            const float r0 = __builtin_amdgcn_rcpf(1.f + e0);
            const float r1 = __builtin_amdgcn_rcpf(1.f + e1);
            acc[s] = fmaf(pre0 * r0, w2.x, acc[s]);
            acc[s] = fmaf(pre1 * r1, w2.y, acc[s]);
        }
    }

    // epilogue: v[i] = sum_j coeff(i,j) * diff(i,j)  — block reduction
    const float b2v  = b2[0];
    const int   wave = tid >> 6;
    const int   lane = tid & 63;
    __shared__ float vsh[4][IT][3];

#pragma unroll
    for (int s = 0; s < IT; ++s) {
        const float coeff = acc[s] + b2v;
        float vx = coeff * dx[s];
        float vy = coeff * dy[s];
        float vz = coeff * dz[s];
#pragma unroll
        for (int off = 32; off >= 1; off >>= 1) {
            vx += __shfl_xor(vx, off, 64);
            vy += __shfl_xor(vy, off, 64);
            vz += __shfl_xor(vz, off, 64);
        }
        if (lane == 0) {
            vsh[wave][s][0] = vx; vsh[wave][s][1] = vy; vsh[wave][s][2] = vz;
        }
    }
    __syncthreads();
    if (tid < IT * 3) {
        const int s = tid / 3, comp = tid % 3;
        out[(brow + i0 + s) * 3 + comp] =
            vsh[0][s][comp] + vsh[1][s][comp] + vsh[2][s][comp] + vsh[3][s][comp];
    }
}

extern "C" void kernel_launch(void* const* d_in, const int* in_sizes, int n_in,
                              void* d_out, int out_size, void* d_ws, size_t ws_size,
                              hipStream_t stream) {
    const float* h   = (const float*)d_in[0];  // (2048, 128)
    const float* pos = (const float*)d_in[1];  // (2048, 3)
    // d_in[2] = batch indices (int64) — contiguous per batch, unused
    const float* W1  = (const float*)d_in[3];  // (257, 128)
    const float* b1  = (const float*)d_in[4];  // (128,)
    const float* W2  = (const float*)d_in[5];  // (128, 1)
    const float* b2  = (const float*)d_in[6];  // (1,)
    float* out = (float*)d_out;                // (2048, 3)

    float* A_T2 = (float*)d_ws;                // 2048*128 floats = 1 MB
    float* Bb   = A_T2 + TOTAL * HDIM;         // 2048*128 floats = 1 MB

    evh_prep_kernel<<<TOTAL, HDIM, 0, stream>>>(h, W1, b1, A_T2, Bb);
    evh_pair_kernel<<<TOTAL / IT, 256, 0, stream>>>(A_T2, Bb, pos, W1, W2, b2, out);
}

// Round 3
// 35.872 us; speedup vs baseline: 2.3549x; 1.0564x over previous
//
#include <hip/hip_runtime.h>
#include <math.h>

#define BATCH 8
#define NPTS  256
#define HDIM  128
#define TOTAL (BATCH * NPTS)   // 2048
#define IT    2                // targets (i) per block in the pair kernel

#define NEG_LOG2E -1.4426950408889634f
#define NEG_LN2   -0.6931471805599453f

// ---------------------------------------------------------------------------
// Kernel 1: per-row projections with constant folding for the pair phase.
//   A'[t,c]  = (h@Wa)[t,c] * (-log2e)   stored quad-interleaved channel-major:
//              A_T4[(c>>2)*4*TOTAL + 4*t + (c&3)]
//   Bb'[t,c] = ((h@Wb)[t,c] + b1[c]) * (-log2e)   row-major
// Then pre2 = A' + Bb' + dist*wd' satisfies exp(-pre) = 2^pre2.
// ---------------------------------------------------------------------------
__global__ __launch_bounds__(HDIM) void evh_prep_kernel(
    const float* __restrict__ h, const float* __restrict__ W1,
    const float* __restrict__ b1, float* __restrict__ A_T4,
    float* __restrict__ Bb)
{
    __shared__ float hrow[HDIM];
    const int t = blockIdx.x;
    const int c = threadIdx.x;
    hrow[c] = h[t * HDIM + c];
    __syncthreads();

    float a = 0.f, bsum = 0.f;
#pragma unroll 8
    for (int k = 0; k < HDIM; ++k) {
        const float hv = hrow[k];
        a    = fmaf(hv, W1[k * HDIM + c], a);
        bsum = fmaf(hv, W1[(HDIM + k) * HDIM + c], bsum);
    }
    A_T4[(c >> 2) * (4 * TOTAL) + 4 * t + (c & 3)] = a * NEG_LOG2E;
    Bb[t * HDIM + c] = (bsum + b1[c]) * NEG_LOG2E;
}

// ---------------------------------------------------------------------------
// Kernel 2: pairwise pass. Block = (batch b, IT targets). 256 threads = j.
// Per 4-channel group: one coalesced dwordx4 A' load + uniform ds_read_b128
// param broadcasts; silu+dot accumulates in registers. One exp2 + one rcp
// per cell, zero cross-lane ops in the hot loop.
// ---------------------------------------------------------------------------
__global__ __launch_bounds__(256) void evh_pair_kernel(
    const float* __restrict__ A_T4, const float* __restrict__ Bb,
    const float* __restrict__ pos, const float* __restrict__ W1,
    const float* __restrict__ W2, const float* __restrict__ b2,
    float* __restrict__ out)
{
    const int blk = blockIdx.x;                 // 0 .. 1023
    const int b   = blk >> 7;                   // NPTS/IT = 128 blocks/batch
    const int i0  = (blk & 127) * IT;
    const int tid = threadIdx.x;                // = j within batch
    const int brow  = b * NPTS;
    const int row_j = brow + tid;

    __shared__ float4 wdq[HDIM / 4], w2q[HDIM / 4], bbq[IT][HDIM / 4];
    if (tid < 32) {
        const float* wdp = W1 + 2 * HDIM * HDIM;
        const float4 w = *reinterpret_cast<const float4*>(wdp + 4 * tid);
        wdq[tid] = make_float4(w.x * NEG_LOG2E, w.y * NEG_LOG2E,
                               w.z * NEG_LOG2E, w.w * NEG_LOG2E);
        const float4 v = *reinterpret_cast<const float4*>(W2 + 4 * tid);
        w2q[tid] = make_float4(v.x * NEG_LN2, v.y * NEG_LN2,
                               v.z * NEG_LN2, v.w * NEG_LN2);
    } else if (tid < 32 + IT * 32) {
        const int s = (tid - 32) >> 5;
        const int q = (tid - 32) & 31;
        bbq[s][q] = *reinterpret_cast<const float4*>(
                        &Bb[(brow + i0 + s) * HDIM + 4 * q]);
    }

    const float pjx = pos[row_j * 3 + 0];
    const float pjy = pos[row_j * 3 + 1];
    const float pjz = pos[row_j * 3 + 2];

    float dx[IT], dy[IT], dz[IT], dist[IT];
#pragma unroll
    for (int s = 0; s < IT; ++s) {
        const int row_i = brow + i0 + s;
        dx[s] = pjx - pos[row_i * 3 + 0];
        dy[s] = pjy - pos[row_i * 3 + 1];
        dz[s] = pjz - pos[row_i * 3 + 2];
        dist[s] = sqrtf(dx[s] * dx[s] + dy[s] * dy[s] + dz[s] * dz[s]);
    }
    __syncthreads();

    float acc0 = 0.f, acc1 = 0.f;
    const float* aptr = A_T4 + 4 * row_j;

#define CELL(AK, BK, WDK, W2K, ACC, D)                                  \
    {                                                                   \
        const float pre2 = fmaf((D), (WDK), (AK) + (BK));               \
        const float e = __builtin_amdgcn_exp2f(pre2);                   \
        const float r = __builtin_amdgcn_rcpf(1.f + e);                 \
        ACC = fmaf((W2K), pre2 * r, ACC);                               \
    }

#pragma unroll 4
    for (int c4 = 0; c4 < HDIM / 4; ++c4) {
        const float4 a   = *reinterpret_cast<const float4*>(
                               aptr + c4 * (4 * TOTAL));
        const float4 wd  = wdq[c4];
        const float4 w2  = w2q[c4];
        const float4 bb0 = bbq[0][c4];
        const float4 bb1 = bbq[1][c4];

        CELL(a.x, bb0.x, wd.x, w2.x, acc0, dist[0])
        CELL(a.y, bb0.y, wd.y, w2.y, acc0, dist[0])
        CELL(a.z, bb0.z, wd.z, w2.z, acc0, dist[0])
        CELL(a.w, bb0.w, wd.w, w2.w, acc0, dist[0])
        CELL(a.x, bb1.x, wd.x, w2.x, acc1, dist[1])
        CELL(a.y, bb1.y, wd.y, w2.y, acc1, dist[1])
        CELL(a.z, bb1.z, wd.z, w2.z, acc1, dist[1])
        CELL(a.w, bb1.w, wd.w, w2.w, acc1, dist[1])
    }
#undef CELL

    // epilogue: v[i] = sum_j coeff(i,j) * diff(i,j)
    const float b2v  = b2[0];
    const int   wave = tid >> 6;
    const int   lane = tid & 63;
    __shared__ float vsh[4][IT][3];

    float accs[IT] = {acc0, acc1};
#pragma unroll
    for (int s = 0; s < IT; ++s) {
        const float coeff = accs[s] + b2v;
        float vx = coeff * dx[s];
        float vy = coeff * dy[s];
        float vz = coeff * dz[s];
#pragma unroll
        for (int off = 32; off >= 1; off >>= 1) {
            vx += __shfl_xor(vx, off, 64);
            vy += __shfl_xor(vy, off, 64);
            vz += __shfl_xor(vz, off, 64);
        }
        if (lane == 0) {
            vsh[wave][s][0] = vx; vsh[wave][s][1] = vy; vsh[wave][s][2] = vz;
        }
    }
    __syncthreads();
    if (tid < IT * 3) {
        const int s = tid / 3, comp = tid % 3;
        out[(brow + i0 + s) * 3 + comp] =
            vsh[0][s][comp] + vsh[1][s][comp] + vsh[2][s][comp] + vsh[3][s][comp];
    }
}

extern "C" void kernel_launch(void* const* d_in, const int* in_sizes, int n_in,
                              void* d_out, int out_size, void* d_ws, size_t ws_size,
                              hipStream_t stream) {
    const float* h   = (const float*)d_in[0];  // (2048, 128)
    const float* pos = (const float*)d_in[1];  // (2048, 3)
    // d_in[2] = batch indices (int64) — contiguous per batch, unused
    const float* W1  = (const float*)d_in[3];  // (257, 128)
    const float* b1  = (const float*)d_in[4];  // (128,)
    const float* W2  = (const float*)d_in[5];  // (128, 1)
    const float* b2  = (const float*)d_in[6];  // (1,)
    float* out = (float*)d_out;                // (2048, 3)

    float* A_T4 = (float*)d_ws;                // 2048*128 floats = 1 MB
    float* Bb   = A_T4 + TOTAL * HDIM;         // 2048*128 floats = 1 MB

    evh_prep_kernel<<<TOTAL, HDIM, 0, stream>>>(h, W1, b1, A_T4, Bb);
    evh_pair_kernel<<<TOTAL / IT, 256, 0, stream>>>(A_T4, Bb, pos, W1, W2, b2, out);
}

// Round 4
// 33.671 us; speedup vs baseline: 2.5089x; 1.0654x over previous
//
#include <hip/hip_runtime.h>
#include <math.h>

#define BATCH 8
#define NPTS  256
#define HDIM  128
#define TOTAL (BATCH * NPTS)   // 2048

#define NEG_LOG2E -1.4426950408889634f
#define NEG_LN2   -0.6931471805599453f

// ---------------------------------------------------------------------------
// Kernel 1: per-row projections + constant folding + out-zeroing.
//   A'[t,c]  = (h@Wa)[t,c] * (-log2e)   quad-interleaved channel-major:
//              A_T4[(c>>2)*4*TOTAL + 4*t + (c&3)]
//   Bb'[t,c] = ((h@Wb)[t,c] + b1[c]) * (-log2e)   row-major
//   wdx[c]   = W1[2H,c] * (-log2e),  w2x[c] = W2[c] * (-ln2)   (block 0)
// Then pre2 = A' + Bb' + dist*wdx gives silu(pre)*W2 = w2x * pre2/(1+2^pre2).
// Also zeroes out[] so the pair kernel can atomicAdd (graph-replay safe:
// prep precedes pair in stream order every call).
// ---------------------------------------------------------------------------
__global__ __launch_bounds__(HDIM) void evh_prep_kernel(
    const float* __restrict__ h, const float* __restrict__ W1,
    const float* __restrict__ b1, const float* __restrict__ W2,
    float* __restrict__ A_T4, float* __restrict__ Bb,
    float* __restrict__ wdx, float* __restrict__ w2x,
    float* __restrict__ out)
{
    __shared__ float hrow[HDIM];
    const int t = blockIdx.x;
    const int c = threadIdx.x;
    hrow[c] = h[t * HDIM + c];
    if (t == 0) {
        wdx[c] = W1[2 * HDIM * HDIM + c] * NEG_LOG2E;
        w2x[c] = W2[c] * NEG_LN2;
    }
    if (c < 3) out[t * 3 + c] = 0.f;
    __syncthreads();

    float a = 0.f, bsum = 0.f;
#pragma unroll 8
    for (int k = 0; k < HDIM; ++k) {
        const float hv = hrow[k];
        a    = fmaf(hv, W1[k * HDIM + c], a);
        bsum = fmaf(hv, W1[(HDIM + k) * HDIM + c], bsum);
    }
    A_T4[(c >> 2) * (4 * TOTAL) + 4 * t + (c & 3)] = a * NEG_LOG2E;
    Bb[t * HDIM + c] = (bsum + b1[c]) * NEG_LOG2E;
}

// ---------------------------------------------------------------------------
// Kernel 2: pairwise pass, channel-split.
// Block = (batch b, target-pair i0..i0+1, channel-half ch). 2048 blocks,
// 256 threads = source j. Each thread: 2 i's x 64 channels = 128 cells.
// Uniform operands (Bb' rows, wdx, w2x) are loaded from block-uniform
// addresses -> scalar loads (constant cache); A' loads are coalesced
// dwordx4. No LDS in the hot loop. Partial v -> atomicAdd.
// ---------------------------------------------------------------------------
__global__ __launch_bounds__(256) void evh_pair_kernel(
    const float* __restrict__ A_T4, const float* __restrict__ Bb,
    const float* __restrict__ wdx, const float* __restrict__ w2x,
    const float* __restrict__ pos, const float* __restrict__ b2,
    float* __restrict__ out)
{
    const int blk = blockIdx.x;                 // 0..2047
    const int ch  = blk & 1;                    // channel half
    const int b   = blk >> 8;                   // batch
    const int i0  = ((blk >> 1) & 127) * 2;     // target pair base
    const int tid = threadIdx.x;                // = j within batch
    const int brow  = b * NPTS;
    const int row_j = brow + tid;

    const float pjx = pos[row_j * 3 + 0];
    const float pjy = pos[row_j * 3 + 1];
    const float pjz = pos[row_j * 3 + 2];

    float dx0, dy0, dz0, dist0, dx1, dy1, dz1, dist1;
    {
        const int r0 = brow + i0, r1 = r0 + 1;
        dx0 = pjx - pos[r0 * 3 + 0];
        dy0 = pjy - pos[r0 * 3 + 1];
        dz0 = pjz - pos[r0 * 3 + 2];
        dist0 = sqrtf(dx0 * dx0 + dy0 * dy0 + dz0 * dz0);
        dx1 = pjx - pos[r1 * 3 + 0];
        dy1 = pjy - pos[r1 * 3 + 1];
        dz1 = pjz - pos[r1 * 3 + 2];
        dist1 = sqrtf(dx1 * dx1 + dy1 * dy1 + dz1 * dz1);
    }

    // block-uniform operand pointers (scalar-load friendly)
    const float* __restrict__ bb0p = Bb + (size_t)(brow + i0) * HDIM + ch * 64;
    const float* __restrict__ bb1p = bb0p + HDIM;
    const float* __restrict__ wdp  = wdx + ch * 64;
    const float* __restrict__ w2p  = w2x + ch * 64;
    const float* __restrict__ ap   = A_T4 + 4 * row_j
                                     + (size_t)(ch * 16) * (4 * TOTAL);

    float acc0 = 0.f, acc1 = 0.f;

#define CELL(AK, BK, WDK, W2K, ACC, D)                                  \
    {                                                                   \
        const float pre2 = fmaf((D), (WDK), (AK) + (BK));               \
        const float e = __builtin_amdgcn_exp2f(pre2);                   \
        const float r = __builtin_amdgcn_rcpf(1.f + e);                 \
        ACC = fmaf((W2K), pre2 * r, ACC);                               \
    }

#pragma unroll 4
    for (int q = 0; q < 16; ++q) {
        const float4 a  = *reinterpret_cast<const float4*>(
                              ap + (size_t)q * (4 * TOTAL));
        const float4 b0 = *reinterpret_cast<const float4*>(bb0p + 4 * q);
        const float4 b1 = *reinterpret_cast<const float4*>(bb1p + 4 * q);
        const float4 wd = *reinterpret_cast<const float4*>(wdp + 4 * q);
        const float4 w2 = *reinterpret_cast<const float4*>(w2p + 4 * q);

        CELL(a.x, b0.x, wd.x, w2.x, acc0, dist0)
        CELL(a.y, b0.y, wd.y, w2.y, acc0, dist0)
        CELL(a.z, b0.z, wd.z, w2.z, acc0, dist0)
        CELL(a.w, b0.w, wd.w, w2.w, acc0, dist0)
        CELL(a.x, b1.x, wd.x, w2.x, acc1, dist1)
        CELL(a.y, b1.y, wd.y, w2.y, acc1, dist1)
        CELL(a.z, b1.z, wd.z, w2.z, acc1, dist1)
        CELL(a.w, b1.w, wd.w, w2.w, acc1, dist1)
    }
#undef CELL

    // epilogue: partial v[i] = sum_j coeff(i,j) * diff(i,j) over this
    // channel-half; b2 contributed only by half 0.
    const float cext = (ch == 0) ? b2[0] : 0.f;
    const int wave = tid >> 6;
    const int lane = tid & 63;

    const float c0 = acc0 + cext;
    const float c1 = acc1 + cext;
    float v0x = c0 * dx0, v0y = c0 * dy0, v0z = c0 * dz0;
    float v1x = c1 * dx1, v1y = c1 * dy1, v1z = c1 * dz1;
#pragma unroll
    for (int off = 32; off >= 1; off >>= 1) {
        v0x += __shfl_xor(v0x, off, 64);
        v0y += __shfl_xor(v0y, off, 64);
        v0z += __shfl_xor(v0z, off, 64);
        v1x += __shfl_xor(v1x, off, 64);
        v1y += __shfl_xor(v1y, off, 64);
        v1z += __shfl_xor(v1z, off, 64);
    }

    __shared__ float vsh[4][6];
    if (lane == 0) {
        vsh[wave][0] = v0x; vsh[wave][1] = v0y; vsh[wave][2] = v0z;
        vsh[wave][3] = v1x; vsh[wave][4] = v1y; vsh[wave][5] = v1z;
    }
    __syncthreads();
    if (tid < 6) {
        const float val = vsh[0][tid] + vsh[1][tid] + vsh[2][tid] + vsh[3][tid];
        const int s = tid / 3, comp = tid % 3;
        atomicAdd(&out[(brow + i0 + s) * 3 + comp], val);
    }
}

extern "C" void kernel_launch(void* const* d_in, const int* in_sizes, int n_in,
                              void* d_out, int out_size, void* d_ws, size_t ws_size,
                              hipStream_t stream) {
    const float* h   = (const float*)d_in[0];  // (2048, 128)
    const float* pos = (const float*)d_in[1];  // (2048, 3)
    // d_in[2] = batch indices (int64) — contiguous per batch, unused
    const float* W1  = (const float*)d_in[3];  // (257, 128)
    const float* b1  = (const float*)d_in[4];  // (128,)
    const float* W2  = (const float*)d_in[5];  // (128, 1)
    const float* b2  = (const float*)d_in[6];  // (1,)
    float* out = (float*)d_out;                // (2048, 3)

    float* A_T4 = (float*)d_ws;                // 1 MB
    float* Bb   = A_T4 + TOTAL * HDIM;         // 1 MB
    float* wdx  = Bb + TOTAL * HDIM;           // 512 B
    float* w2x  = wdx + HDIM;                  // 512 B

    evh_prep_kernel<<<TOTAL, HDIM, 0, stream>>>(h, W1, b1, W2,
                                                A_T4, Bb, wdx, w2x, out);
    evh_pair_kernel<<<TOTAL, 256, 0, stream>>>(A_T4, Bb, wdx, w2x,
                                               pos, b2, out);
}